// Round 1
// baseline (922.905 us; speedup 1.0000x reference)
//
#include <hip/hip_runtime.h>
#include <math.h>

#define IN_CH 13
#define HIDDEN 20
#define NCLS 10
#define NBASIS 8
#define NGRID 12
#define NTHREADS 256
#define KAN_NT 64

// All inputs/outputs are fp32 (verified: fp32 path passed absmax=0.0).

// depthwise 3x3 stride-2 pad-1 conv, compile-time sizes, relu epilogue.
// For every stage shape used here (64->32, 32->16, 16->8, 8->4, 4->2):
//   iy = 2*oy-1+ky <= 2*(OW-1)+1 = IW-1  and likewise for ix,
// so only the LOWER bound can fail -> drop the upper-bound compares.
template<int IW, int OW>
__device__ inline void dwconv3t(const float* __restrict__ in, float* __restrict__ out,
                                const float* __restrict__ w, float bias, int tid) {
    constexpr int N = OW * OW;
    constexpr int ITER = (N + NTHREADS - 1) / NTHREADS;
    #pragma unroll
    for (int r = 0; r < ITER; ++r) {
        int o = tid + r * NTHREADS;
        if (N >= NTHREADS || o < N) {
            int oy = o / OW, ox = o % OW;      // OW pow2 -> shifts/masks
            float acc = bias;
            #pragma unroll
            for (int ky = 0; ky < 3; ++ky) {
                int iy = 2 * oy - 1 + ky;
                bool yok = (iy >= 0);
                #pragma unroll
                for (int kx = 0; kx < 3; ++kx) {
                    int ix = 2 * ox - 1 + kx;
                    float v = (yok && ix >= 0) ? in[iy * IW + ix] : 0.0f;
                    acc = fmaf(w[ky * 3 + kx], v, acc);
                }
            }
            out[o] = fmaxf(acc, 0.0f);
        }
    }
}

__global__ __launch_bounds__(NTHREADS) void conv_pipeline(
    const float* __restrict__ x,
    const float* __restrict__ w1, const float* __restrict__ b1,
    const float* __restrict__ w2, const float* __restrict__ b2,
    const float* __restrict__ w3, const float* __restrict__ b3,
    const float* __restrict__ w4, const float* __restrict__ b4,
    const float* __restrict__ w5, const float* __restrict__ b5,
    const float* __restrict__ w6, const float* __restrict__ b6,
    float* __restrict__ h)
{
    __shared__ float sA[64 * 64];
    __shared__ float sB[32 * 32];
    __shared__ float sw[49];
    __shared__ float sbias[6];

    int tid = threadIdx.x;
    int bc = blockIdx.x;              // b*13 + c
    int c = bc % IN_CH;

    if (tid < 9) {
        sw[tid]      = w1[c * 9 + tid];
        sw[9 + tid]  = w2[c * 9 + tid];
        sw[18 + tid] = w3[c * 9 + tid];
        sw[27 + tid] = w4[c * 9 + tid];
        sw[36 + tid] = w5[c * 9 + tid];
    }
    if (tid < 4) sw[45 + tid] = w6[c * 4 + tid];
    if (tid == 0) {
        sbias[0] = b1[c]; sbias[1] = b2[c]; sbias[2] = b3[c];
        sbias[3] = b4[c]; sbias[4] = b5[c]; sbias[5] = b6[c];
    }

    // stage 64x64 fp32 tile -> LDS; 16B global loads, 16B LDS stores
    const float4* xv = reinterpret_cast<const float4*>(x + (size_t)bc * 4096);
    float4* sAv = reinterpret_cast<float4*>(sA);
    #pragma unroll
    for (int i = 0; i < 4; ++i) {
        int v = tid + i * NTHREADS;   // 0..1023 float4 slots
        sAv[v] = xv[v];
    }
    __syncthreads();

    dwconv3t<64, 32>(sA, sB, sw,      sbias[0], tid); __syncthreads();
    dwconv3t<32, 16>(sB, sA, sw + 9,  sbias[1], tid); __syncthreads();
    dwconv3t<16,  8>(sA, sB, sw + 18, sbias[2], tid); __syncthreads();
    dwconv3t< 8,  4>(sB, sA, sw + 27, sbias[3], tid); __syncthreads();
    dwconv3t< 4,  2>(sA, sB, sw + 36, sbias[4], tid); __syncthreads();

    if (tid == 0) {
        // conv6: 2x2 kernel, stride 1, no pad, no relu
        float acc = sbias[5]
                  + sw[45] * sB[0] + sw[46] * sB[1]
                  + sw[47] * sB[2] + sw[48] * sB[3];
        h[bc] = acc;
    }
}

// One KAN layer, exact-arithmetic support-restricted cubic B-spline.
// A cubic B-spline basis has <=4 nonzero entries (indices j0-3..j0 where
// xv in [g[j0], g[j0+1})). The reference's full recursion computes exact
// fp zeros everywhere else (left/right factors are always finite, and
// finite*0 + finite*0 == +0), so restricting the recursion to the support
// reproduces BIT-IDENTICAL basis values with 12 divides instead of 54.
template<int NIN, int NOUT>
__device__ inline void kan_layer(const float* xin, float* xout,
                                 const float* __restrict__ sg,
                                 const float* __restrict__ sc,
                                 const float* __restrict__ ssb,
                                 const float* __restrict__ sss,
                                 const float* __restrict__ sbias)
{
    #pragma unroll
    for (int o = 0; o < NOUT; ++o) xout[o] = sbias[o];

    #pragma unroll
    for (int i = 0; i < NIN; ++i) {
        float xv = xin[i];
        float base = xv / (1.0f + expf(-xv));   // silu, identical to before
        const float* g = sg + i * NGRID;

        // interval index via branchless predicate count:
        // j0 = (#{j : xv >= g[j]}) - 1 ; matches half-open [g[j],g[j+1})
        int cnt = 0;
        #pragma unroll
        for (int j = 0; j < NGRID; ++j) cnt += (xv >= g[j]) ? 1 : 0;
        int j0 = cnt - 1;   // in [-1, 11]; spline support valid only for [0,10]

        // slot k <-> basis index j0-3+k (k=0..3)
        float b0 = 0.f, b1 = 0.f, b2 = 0.f;
        float b3 = (j0 >= 0 && j0 <= NGRID - 2) ? 1.f : 0.f;  // degree 0

        // p = 1  (valid j range [0, NGRID-3])
        {
            int j = j0 - 1;
            float v = 0.f;
            if (j >= 0 && j <= NGRID - 3)
                v = (g[j + 2] - xv) / (g[j + 2] - g[j + 1]) * b3;   // right only
            b2 = v;
            j = j0;
            v = 0.f;
            if (j >= 0 && j <= NGRID - 3)
                v = (xv - g[j]) / (g[j + 1] - g[j]) * b3;           // left only
            b3 = v;
        }
        // p = 2  (valid j range [0, NGRID-4])
        {
            int j = j0 - 2;
            float v = 0.f;
            if (j >= 0 && j <= NGRID - 4)
                v = (g[j + 3] - xv) / (g[j + 3] - g[j + 1]) * b2;
            b1 = v;
            j = j0 - 1;
            v = 0.f;
            if (j >= 0 && j <= NGRID - 4)
                v = (xv - g[j]) / (g[j + 2] - g[j]) * b2
                  + (g[j + 3] - xv) / (g[j + 3] - g[j + 1]) * b3;
            b2 = v;
            j = j0;
            v = 0.f;
            if (j >= 0 && j <= NGRID - 4)
                v = (xv - g[j]) / (g[j + 2] - g[j]) * b3;
            b3 = v;
        }
        // p = 3  (valid j range [0, NGRID-5])
        {
            int j = j0 - 3;
            float v = 0.f;
            if (j >= 0 && j <= NGRID - 5)
                v = (g[j + 4] - xv) / (g[j + 4] - g[j + 1]) * b1;
            b0 = v;
            j = j0 - 2;
            v = 0.f;
            if (j >= 0 && j <= NGRID - 5)
                v = (xv - g[j]) / (g[j + 3] - g[j]) * b1
                  + (g[j + 4] - xv) / (g[j + 4] - g[j + 1]) * b2;
            b1 = v;
            j = j0 - 1;
            v = 0.f;
            if (j >= 0 && j <= NGRID - 5)
                v = (xv - g[j]) / (g[j + 3] - g[j]) * b2
                  + (g[j + 4] - xv) / (g[j + 4] - g[j + 1]) * b3;
            b2 = v;
            j = j0;
            v = 0.f;
            if (j >= 0 && j <= NGRID - 5)
                v = (xv - g[j]) / (g[j + 3] - g[j]) * b3;
            b3 = v;
        }

        // clamped coefficient indices; whenever an index was clamped the
        // matching basis value is exactly +0, so the product contributes +0.
        int n0 = j0 - 3, n1 = j0 - 2, n2 = j0 - 1, n3 = j0;
        n0 = n0 < 0 ? 0 : (n0 > NBASIS - 1 ? NBASIS - 1 : n0);
        n1 = n1 < 0 ? 0 : (n1 > NBASIS - 1 ? NBASIS - 1 : n1);
        n2 = n2 < 0 ? 0 : (n2 > NBASIS - 1 ? NBASIS - 1 : n2);
        n3 = n3 < 0 ? 0 : (n3 > NBASIS - 1 ? NBASIS - 1 : n3);

        #pragma unroll
        for (int o = 0; o < NOUT; ++o) {
            const float* cf = sc + (i * NOUT + o) * NBASIS;
            float sp = b0 * cf[n0] + b1 * cf[n1] + b2 * cf[n2] + b3 * cf[n3];
            xout[o] += base * ssb[i * NOUT + o] + sp * sss[i * NOUT + o];
        }
    }
}

__global__ __launch_bounds__(KAN_NT) void kan_head(
    const float* __restrict__ h,
    const float* __restrict__ grid1, const float* __restrict__ coef1,
    const float* __restrict__ sb1,   const float* __restrict__ ss1,
    const float* __restrict__ bias1,
    const float* __restrict__ grid2, const float* __restrict__ coef2,
    const float* __restrict__ sb2,   const float* __restrict__ ss2,
    const float* __restrict__ bias2,
    float* __restrict__ out, int nsamples)
{
    __shared__ float sg1[IN_CH * NGRID];
    __shared__ float sc1[IN_CH * HIDDEN * NBASIS];
    __shared__ float ssb1[IN_CH * HIDDEN];
    __shared__ float sss1[IN_CH * HIDDEN];
    __shared__ float sbias1[HIDDEN];
    __shared__ float sg2[HIDDEN * NGRID];
    __shared__ float sc2[HIDDEN * NCLS * NBASIS];
    __shared__ float ssb2[HIDDEN * NCLS];
    __shared__ float sss2[HIDDEN * NCLS];
    __shared__ float sbias2[NCLS];

    int tid = threadIdx.x;
    for (int i = tid; i < IN_CH * NGRID; i += KAN_NT)           sg1[i] = grid1[i];
    for (int i = tid; i < IN_CH * HIDDEN * NBASIS; i += KAN_NT) sc1[i] = coef1[i];
    for (int i = tid; i < IN_CH * HIDDEN; i += KAN_NT)          ssb1[i] = sb1[i];
    for (int i = tid; i < IN_CH * HIDDEN; i += KAN_NT)          sss1[i] = ss1[i];
    for (int i = tid; i < HIDDEN; i += KAN_NT)                  sbias1[i] = bias1[i];
    for (int i = tid; i < HIDDEN * NGRID; i += KAN_NT)          sg2[i] = grid2[i];
    for (int i = tid; i < HIDDEN * NCLS * NBASIS; i += KAN_NT)  sc2[i] = coef2[i];
    for (int i = tid; i < HIDDEN * NCLS; i += KAN_NT)           ssb2[i] = sb2[i];
    for (int i = tid; i < HIDDEN * NCLS; i += KAN_NT)           sss2[i] = ss2[i];
    for (int i = tid; i < NCLS; i += KAN_NT)                    sbias2[i] = bias2[i];
    __syncthreads();

    int s = blockIdx.x * KAN_NT + tid;
    if (s >= nsamples) return;

    float xi[IN_CH];
    #pragma unroll
    for (int i = 0; i < IN_CH; ++i) xi[i] = h[s * IN_CH + i];

    float a2[HIDDEN];
    kan_layer<IN_CH, HIDDEN>(xi, a2, sg1, sc1, ssb1, sss1, sbias1);

    float z[NCLS];
    kan_layer<HIDDEN, NCLS>(a2, z, sg2, sc2, ssb2, sss2, sbias2);

    // ---- log_softmax ----
    float m = z[0];
    #pragma unroll
    for (int o = 1; o < NCLS; ++o) m = fmaxf(m, z[o]);
    float sum = 0.0f;
    #pragma unroll
    for (int o = 0; o < NCLS; ++o) sum += expf(z[o] - m);
    float lse = logf(sum) + m;
    #pragma unroll
    for (int o = 0; o < NCLS; ++o) out[s * NCLS + o] = z[o] - lse;
}

extern "C" void kernel_launch(void* const* d_in, const int* in_sizes, int n_in,
                              void* d_out, int out_size, void* d_ws, size_t ws_size,
                              hipStream_t stream) {
    const float* x  = (const float*)d_in[0];
    const float* w1 = (const float*)d_in[1];  const float* b1 = (const float*)d_in[2];
    const float* w2 = (const float*)d_in[3];  const float* b2 = (const float*)d_in[4];
    const float* w3 = (const float*)d_in[5];  const float* b3 = (const float*)d_in[6];
    const float* w4 = (const float*)d_in[7];  const float* b4 = (const float*)d_in[8];
    const float* w5 = (const float*)d_in[9];  const float* b5 = (const float*)d_in[10];
    const float* w6 = (const float*)d_in[11]; const float* b6 = (const float*)d_in[12];
    const float* grid1 = (const float*)d_in[13];
    const float* coef1 = (const float*)d_in[14];
    const float* sb1   = (const float*)d_in[15];
    const float* ss1   = (const float*)d_in[16];
    const float* bias1 = (const float*)d_in[17];
    const float* grid2 = (const float*)d_in[18];
    const float* coef2 = (const float*)d_in[19];
    const float* sb2   = (const float*)d_in[20];
    const float* ss2   = (const float*)d_in[21];
    const float* bias2 = (const float*)d_in[22];

    int B = in_sizes[0] / (IN_CH * 64 * 64);     // 2048
    float* h = (float*)d_ws;                      // B*IN_CH fp32

    conv_pipeline<<<B * IN_CH, NTHREADS, 0, stream>>>(
        x, w1, b1, w2, b2, w3, b3, w4, b4, w5, b5, w6, b6, h);

    kan_head<<<(B + KAN_NT - 1) / KAN_NT, KAN_NT, 0, stream>>>(
        h, grid1, coef1, sb1, ss1, bias1, grid2, coef2, sb2, ss2, bias2,
        (float*)d_out, B);
}

// Round 2
// 638.424 us; speedup vs baseline: 1.4456x; 1.4456x over previous
//
#include <hip/hip_runtime.h>
#include <math.h>

#define IN_CH 13
#define HIDDEN 20
#define NCLS 10
#define NBASIS 8
#define NGRID 12
#define NTHREADS 256

#define KAN_T 4                    // threads cooperating on one sample
#define KAN_BS 64                  // block size (1 wave)
#define SPB (KAN_BS / KAN_T)       // 16 samples per block

// All inputs/outputs are fp32 (verified: fp32 path passed absmax=0.0).

// depthwise 3x3 stride-2 pad-1 conv, compile-time sizes, relu epilogue.
// For every stage shape used here only the LOWER bound can fail.
template<int IW, int OW>
__device__ inline void dwconv3t(const float* __restrict__ in, float* __restrict__ out,
                                const float* __restrict__ w, float bias, int tid) {
    constexpr int N = OW * OW;
    constexpr int ITER = (N + NTHREADS - 1) / NTHREADS;
    #pragma unroll
    for (int r = 0; r < ITER; ++r) {
        int o = tid + r * NTHREADS;
        if (N >= NTHREADS || o < N) {
            int oy = o / OW, ox = o % OW;      // OW pow2 -> shifts/masks
            float acc = bias;
            #pragma unroll
            for (int ky = 0; ky < 3; ++ky) {
                int iy = 2 * oy - 1 + ky;
                bool yok = (iy >= 0);
                #pragma unroll
                for (int kx = 0; kx < 3; ++kx) {
                    int ix = 2 * ox - 1 + kx;
                    float v = (yok && ix >= 0) ? in[iy * IW + ix] : 0.0f;
                    acc = fmaf(w[ky * 3 + kx], v, acc);
                }
            }
            out[o] = fmaxf(acc, 0.0f);
        }
    }
}

__global__ __launch_bounds__(NTHREADS) void conv_pipeline(
    const float* __restrict__ x,
    const float* __restrict__ w1, const float* __restrict__ b1,
    const float* __restrict__ w2, const float* __restrict__ b2,
    const float* __restrict__ w3, const float* __restrict__ b3,
    const float* __restrict__ w4, const float* __restrict__ b4,
    const float* __restrict__ w5, const float* __restrict__ b5,
    const float* __restrict__ w6, const float* __restrict__ b6,
    float* __restrict__ h)
{
    __shared__ float sA[64 * 64];
    __shared__ float sB[32 * 32];
    __shared__ float sw[49];
    __shared__ float sbias[6];

    int tid = threadIdx.x;
    int bc = blockIdx.x;              // b*13 + c
    int c = bc % IN_CH;

    if (tid < 9) {
        sw[tid]      = w1[c * 9 + tid];
        sw[9 + tid]  = w2[c * 9 + tid];
        sw[18 + tid] = w3[c * 9 + tid];
        sw[27 + tid] = w4[c * 9 + tid];
        sw[36 + tid] = w5[c * 9 + tid];
    }
    if (tid < 4) sw[45 + tid] = w6[c * 4 + tid];
    if (tid == 0) {
        sbias[0] = b1[c]; sbias[1] = b2[c]; sbias[2] = b3[c];
        sbias[3] = b4[c]; sbias[4] = b5[c]; sbias[5] = b6[c];
    }

    const float4* xv = reinterpret_cast<const float4*>(x + (size_t)bc * 4096);
    float4* sAv = reinterpret_cast<float4*>(sA);
    #pragma unroll
    for (int i = 0; i < 4; ++i) {
        int v = tid + i * NTHREADS;
        sAv[v] = xv[v];
    }
    __syncthreads();

    dwconv3t<64, 32>(sA, sB, sw,      sbias[0], tid); __syncthreads();
    dwconv3t<32, 16>(sB, sA, sw + 9,  sbias[1], tid); __syncthreads();
    dwconv3t<16,  8>(sA, sB, sw + 18, sbias[2], tid); __syncthreads();
    dwconv3t< 8,  4>(sB, sA, sw + 27, sbias[3], tid); __syncthreads();
    dwconv3t< 4,  2>(sA, sB, sw + 36, sbias[4], tid); __syncthreads();

    if (tid == 0) {
        float acc = sbias[5]
                  + sw[45] * sB[0] + sw[46] * sB[1]
                  + sw[47] * sB[2] + sw[48] * sB[3];
        h[bc] = acc;
    }
}

// Support-restricted cubic B-spline: bit-identical to the full Cox-de Boor
// recursion (verified absmax=0.0 in round 1), 12 divides instead of 54.
// Outputs: 4 basis values b0..b3 for indices j0-3..j0 and clamped
// coefficient indices n0..n3 (clamped index <=> basis value is exactly +0).
__device__ inline void spline4(float xv, const float* __restrict__ g,
                               float& b0, float& b1, float& b2, float& b3,
                               int& n0, int& n1, int& n2, int& n3)
{
    int cnt = 0;
    #pragma unroll
    for (int j = 0; j < NGRID; ++j) cnt += (xv >= g[j]) ? 1 : 0;
    int j0 = cnt - 1;

    b0 = 0.f; b1 = 0.f; b2 = 0.f;
    b3 = (j0 >= 0 && j0 <= NGRID - 2) ? 1.f : 0.f;

    { // p = 1
        int j = j0 - 1;
        float v = 0.f;
        if (j >= 0 && j <= NGRID - 3)
            v = (g[j + 2] - xv) / (g[j + 2] - g[j + 1]) * b3;
        b2 = v;
        j = j0;
        v = 0.f;
        if (j >= 0 && j <= NGRID - 3)
            v = (xv - g[j]) / (g[j + 1] - g[j]) * b3;
        b3 = v;
    }
    { // p = 2
        int j = j0 - 2;
        float v = 0.f;
        if (j >= 0 && j <= NGRID - 4)
            v = (g[j + 3] - xv) / (g[j + 3] - g[j + 1]) * b2;
        b1 = v;
        j = j0 - 1;
        v = 0.f;
        if (j >= 0 && j <= NGRID - 4)
            v = (xv - g[j]) / (g[j + 2] - g[j]) * b2
              + (g[j + 3] - xv) / (g[j + 3] - g[j + 1]) * b3;
        b2 = v;
        j = j0;
        v = 0.f;
        if (j >= 0 && j <= NGRID - 4)
            v = (xv - g[j]) / (g[j + 2] - g[j]) * b3;
        b3 = v;
    }
    { // p = 3
        int j = j0 - 3;
        float v = 0.f;
        if (j >= 0 && j <= NGRID - 5)
            v = (g[j + 4] - xv) / (g[j + 4] - g[j + 1]) * b1;
        b0 = v;
        j = j0 - 2;
        v = 0.f;
        if (j >= 0 && j <= NGRID - 5)
            v = (xv - g[j]) / (g[j + 3] - g[j]) * b1
              + (g[j + 4] - xv) / (g[j + 4] - g[j + 1]) * b2;
        b1 = v;
        j = j0 - 1;
        v = 0.f;
        if (j >= 0 && j <= NGRID - 5)
            v = (xv - g[j]) / (g[j + 3] - g[j]) * b2
              + (g[j + 4] - xv) / (g[j + 4] - g[j + 1]) * b3;
        b2 = v;
        j = j0;
        v = 0.f;
        if (j >= 0 && j <= NGRID - 5)
            v = (xv - g[j]) / (g[j + 3] - g[j]) * b3;
        b3 = v;
    }

    n0 = j0 - 3; n1 = j0 - 2; n2 = j0 - 1; n3 = j0;
    n0 = n0 < 0 ? 0 : (n0 > NBASIS - 1 ? NBASIS - 1 : n0);
    n1 = n1 < 0 ? 0 : (n1 > NBASIS - 1 ? NBASIS - 1 : n1);
    n2 = n2 < 0 ? 0 : (n2 > NBASIS - 1 ? NBASIS - 1 : n2);
    n3 = n3 < 0 ? 0 : (n3 > NBASIS - 1 ? NBASIS - 1 : n3);
}

// 4 threads per sample, split by OUTPUT index -> every output's accumulation
// chain (bias + sum over i in order) is computed serially on ONE thread in
// the exact reference order: zero reassociation, bit-identical results.
// i-loops intentionally NOT unrolled (round-1 lesson: full unroll -> 256
// VGPR + 12 MB scratch spill traffic -> 340 us).
__global__ __launch_bounds__(KAN_BS) void kan_head(
    const float* __restrict__ h,
    const float* __restrict__ grid1, const float* __restrict__ coef1,
    const float* __restrict__ sb1,   const float* __restrict__ ss1,
    const float* __restrict__ bias1,
    const float* __restrict__ grid2, const float* __restrict__ coef2,
    const float* __restrict__ sb2,   const float* __restrict__ ss2,
    const float* __restrict__ bias2,
    float* __restrict__ out, int nsamples)
{
    __shared__ float sg1[IN_CH * NGRID];
    __shared__ float sc1[IN_CH * HIDDEN * NBASIS];
    __shared__ float ssb1[IN_CH * HIDDEN];
    __shared__ float sss1[IN_CH * HIDDEN];
    __shared__ float sbias1[HIDDEN];
    __shared__ float sg2[HIDDEN * NGRID];
    __shared__ float sc2[HIDDEN * NCLS * NBASIS];
    __shared__ float ssb2[HIDDEN * NCLS];
    __shared__ float sss2[HIDDEN * NCLS];
    __shared__ float sbias2[NCLS];
    __shared__ float a2x[SPB][HIDDEN];   // layer-1 output exchange
    __shared__ float zx[SPB][NCLS];      // layer-2 output exchange

    int tid = threadIdx.x;
    for (int i = tid; i < IN_CH * NGRID; i += KAN_BS)           sg1[i] = grid1[i];
    for (int i = tid; i < IN_CH * HIDDEN * NBASIS; i += KAN_BS) sc1[i] = coef1[i];
    for (int i = tid; i < IN_CH * HIDDEN; i += KAN_BS)          ssb1[i] = sb1[i];
    for (int i = tid; i < IN_CH * HIDDEN; i += KAN_BS)          sss1[i] = ss1[i];
    for (int i = tid; i < HIDDEN; i += KAN_BS)                  sbias1[i] = bias1[i];
    for (int i = tid; i < HIDDEN * NGRID; i += KAN_BS)          sg2[i] = grid2[i];
    for (int i = tid; i < HIDDEN * NCLS * NBASIS; i += KAN_BS)  sc2[i] = coef2[i];
    for (int i = tid; i < HIDDEN * NCLS; i += KAN_BS)           ssb2[i] = sb2[i];
    for (int i = tid; i < HIDDEN * NCLS; i += KAN_BS)           sss2[i] = ss2[i];
    for (int i = tid; i < NCLS; i += KAN_BS)                    sbias2[i] = bias2[i];
    __syncthreads();

    int sub = tid & (KAN_T - 1);        // 0..3: which output slice
    int sl  = tid >> 2;                 // 0..15: sample within block
    int s   = blockIdx.x * SPB + sl;
    bool active = (s < nsamples);
    int sld = active ? s : (nsamples - 1);   // clamped for global loads

    // ---- KAN layer 1: 13 -> 20, thread owns outputs [sub*5, sub*5+5) ----
    float acc[5];
    #pragma unroll
    for (int k = 0; k < 5; ++k) acc[k] = sbias1[sub * 5 + k];

    #pragma unroll 1
    for (int i = 0; i < IN_CH; ++i) {
        float xv = h[sld * IN_CH + i];
        float base = xv / (1.0f + expf(-xv));   // silu
        float b0, b1, b2, b3; int n0, n1, n2, n3;
        spline4(xv, sg1 + i * NGRID, b0, b1, b2, b3, n0, n1, n2, n3);
        #pragma unroll
        for (int k = 0; k < 5; ++k) {
            int o = sub * 5 + k;
            const float* cf = sc1 + (i * HIDDEN + o) * NBASIS;
            float sp = b0 * cf[n0] + b1 * cf[n1] + b2 * cf[n2] + b3 * cf[n3];
            acc[k] += base * ssb1[i * HIDDEN + o] + sp * sss1[i * HIDDEN + o];
        }
    }
    #pragma unroll
    for (int k = 0; k < 5; ++k) a2x[sl][sub * 5 + k] = acc[k];
    __syncthreads();

    // ---- KAN layer 2: 20 -> 10, thread owns outputs sub*3..sub*3+2 (<10) ----
    float accz[3];
    #pragma unroll
    for (int k = 0; k < 3; ++k) {
        int o = sub * 3 + k;
        accz[k] = (o < NCLS) ? sbias2[o] : 0.0f;
    }

    #pragma unroll 1
    for (int i = 0; i < HIDDEN; ++i) {
        float xv = a2x[sl][i];
        float base = xv / (1.0f + expf(-xv));
        float b0, b1, b2, b3; int n0, n1, n2, n3;
        spline4(xv, sg2 + i * NGRID, b0, b1, b2, b3, n0, n1, n2, n3);
        #pragma unroll
        for (int k = 0; k < 3; ++k) {
            int o = sub * 3 + k;
            if (o < NCLS) {
                const float* cf = sc2 + (i * NCLS + o) * NBASIS;
                float sp = b0 * cf[n0] + b1 * cf[n1] + b2 * cf[n2] + b3 * cf[n3];
                accz[k] += base * ssb2[i * NCLS + o] + sp * sss2[i * NCLS + o];
            }
        }
    }
    #pragma unroll
    for (int k = 0; k < 3; ++k) {
        int o = sub * 3 + k;
        if (o < NCLS) zx[sl][o] = accz[k];
    }
    __syncthreads();

    // ---- log_softmax (redundant per thread, fixed order -> identical bits) ----
    float m = zx[sl][0];
    #pragma unroll
    for (int o = 1; o < NCLS; ++o) m = fmaxf(m, zx[sl][o]);
    float sum = 0.0f;
    #pragma unroll
    for (int o = 0; o < NCLS; ++o) sum += expf(zx[sl][o] - m);
    float lse = logf(sum) + m;
    if (active) {
        #pragma unroll
        for (int k = 0; k < 3; ++k) {
            int o = sub * 3 + k;
            if (o < NCLS) out[s * NCLS + o] = zx[sl][o] - lse;
        }
    }
}

extern "C" void kernel_launch(void* const* d_in, const int* in_sizes, int n_in,
                              void* d_out, int out_size, void* d_ws, size_t ws_size,
                              hipStream_t stream) {
    const float* x  = (const float*)d_in[0];
    const float* w1 = (const float*)d_in[1];  const float* b1 = (const float*)d_in[2];
    const float* w2 = (const float*)d_in[3];  const float* b2 = (const float*)d_in[4];
    const float* w3 = (const float*)d_in[5];  const float* b3 = (const float*)d_in[6];
    const float* w4 = (const float*)d_in[7];  const float* b4 = (const float*)d_in[8];
    const float* w5 = (const float*)d_in[9];  const float* b5 = (const float*)d_in[10];
    const float* w6 = (const float*)d_in[11]; const float* b6 = (const float*)d_in[12];
    const float* grid1 = (const float*)d_in[13];
    const float* coef1 = (const float*)d_in[14];
    const float* sb1   = (const float*)d_in[15];
    const float* ss1   = (const float*)d_in[16];
    const float* bias1 = (const float*)d_in[17];
    const float* grid2 = (const float*)d_in[18];
    const float* coef2 = (const float*)d_in[19];
    const float* sb2   = (const float*)d_in[20];
    const float* ss2   = (const float*)d_in[21];
    const float* bias2 = (const float*)d_in[22];

    int B = in_sizes[0] / (IN_CH * 64 * 64);     // 2048
    float* h = (float*)d_ws;                      // B*IN_CH fp32

    conv_pipeline<<<B * IN_CH, NTHREADS, 0, stream>>>(
        x, w1, b1, w2, b2, w3, b3, w4, b4, w5, b5, w6, b6, h);

    int nblk = (B + SPB - 1) / SPB;               // 128 blocks x 1 wave
    kan_head<<<nblk, KAN_BS, 0, stream>>>(
        h, grid1, coef1, sb1, ss1, bias1, grid2, coef2, sb2, ss2, bias2,
        (float*)d_out, B);
}